// Round 7
// baseline (519.734 us; speedup 1.0000x reference)
//
#include <hip/hip_runtime.h>
#include <math.h>

// ClassicMHSA via split-bf16 MFMA, LDS-free flash attention (swapped QK^T).
// Round 7: remove the two per-tile structural taxes found in r6 post-mortem:
//  (a) PV is now SHUFFLE-FREE: the PV k-block uses a custom j-bijection
//      slot(g,s) <-> j = 32*k2 + 16*(s>>2) + 4g + (s&3), chosen so the
//      B-fragment is exactly the lane-local packed words pw[2k2..2k2+1][*].
//      V's A-fragment loads the SAME permuted order (two ushort4 per half).
//      Slot-pairing (A(g,s) pairs with B(g,s)) is HW-proven by r1-r6 passing.
//  (b) 32-bit-friendly addressing: K packed hi|lo per row [bh][n][64]; four
//      per-lane pointers advanced by constant strides; all loads base+imm.
// Keeps: XCD swizzle (FETCH 67.7->10.3MB, r5-verified), defer-max, exp2
// domain, per-lane partial l. No LDS ops in attn at all.
//
//  1) xt_split : X[b][c][n] f32 -> Xthi/Xtlo [b][n][c] bf16
//  2) qkv_proj : MFMA GEMM -> Qp/Kp [bh][n][64] (hi|lo packed, Q pre-scaled),
//                Vt [bh][32][n] (hi only)
//  3) attn_mfma: flash attention, QK^T 3-pass split-bf16, PV 1-pass bf16.

#define B_   2
#define CIN  256
#define COUT 768
#define NH   8
#define HD   32
#define NTOK 4096
#define BH   (B_*NH)

// log2(e)/sqrt(32): folds softmax scale + exp->exp2 conversion into Q.
#define QSCALE 0.2550565448497569f
// defer-max threshold in log2 units (P bounded by 2^12; lrun <= 2^24).
#define DEFER_T 12.0f

typedef __attribute__((ext_vector_type(8))) short bf16x8;
typedef __attribute__((ext_vector_type(4))) float f32x4;

static __device__ __forceinline__ unsigned short f2bf(float f) {  // RNE
  unsigned u = __float_as_uint(f);
  unsigned r = ((u >> 16) & 1u) + 0x7fffu;
  return (unsigned short)((u + r) >> 16);
}
static __device__ __forceinline__ float bf2f(unsigned short h) {
  return __uint_as_float(((unsigned)h) << 16);
}
// pack two POSITIVE floats to bf16 pair (round-half-up)
static __device__ __forceinline__ unsigned packbf(float lo, float hi) {
  unsigned a = (__float_as_uint(lo) + 0x8000u) >> 16;
  unsigned b = (__float_as_uint(hi) + 0x8000u) & 0xffff0000u;
  return a | b;
}

// ---------------- 1) X transpose + split (coalesced, LDS transpose) --------
__global__ __launch_bounds__(256) void xt_split(
    const float* __restrict__ X,
    unsigned short* __restrict__ Xthi, unsigned short* __restrict__ Xtlo) {
  __shared__ unsigned tile[64][72];  // hi | lo<<16
  const int t = threadIdx.x;
  const int n0 = blockIdx.x * 64, c0 = blockIdx.y * 64, b = blockIdx.z;
  {
    const int cl = t >> 2, nb = (t & 3) * 16;
    const float* src = &X[((size_t)(b * CIN + c0 + cl)) * NTOK + n0 + nb];
#pragma unroll
    for (int q = 0; q < 4; ++q) {
      float4 v = *(const float4*)&src[4 * q];
      float vv[4] = {v.x, v.y, v.z, v.w};
#pragma unroll
      for (int e = 0; e < 4; ++e) {
        unsigned short h = f2bf(vv[e]);
        unsigned short l = f2bf(vv[e] - bf2f(h));
        tile[cl][nb + 4 * q + e] = (unsigned)h | ((unsigned)l << 16);
      }
    }
  }
  __syncthreads();
  {
    const int nl = t >> 2, cb = (t & 3) * 16;
    unsigned wh[8], wl[8];
#pragma unroll
    for (int j = 0; j < 8; ++j) {
      unsigned a = tile[cb + 2 * j][nl];
      unsigned bb = tile[cb + 2 * j + 1][nl];
      wh[j] = (a & 0xffffu) | (bb << 16);
      wl[j] = (a >> 16) | (bb & 0xffff0000u);
    }
    size_t base = ((size_t)b * NTOK + n0 + nl) * CIN + c0 + cb;
    uint4 u0, u1;
    u0.x = wh[0]; u0.y = wh[1]; u0.z = wh[2]; u0.w = wh[3];
    u1.x = wh[4]; u1.y = wh[5]; u1.z = wh[6]; u1.w = wh[7];
    *(uint4*)&Xthi[base] = u0;
    *(uint4*)&Xthi[base + 8] = u1;
    u0.x = wl[0]; u0.y = wl[1]; u0.z = wl[2]; u0.w = wl[3];
    u1.x = wl[4]; u1.y = wl[5]; u1.z = wl[6]; u1.w = wl[7];
    *(uint4*)&Xtlo[base] = u0;
    *(uint4*)&Xtlo[base + 8] = u1;
  }
}

// ---------------- 2) QKV projection (MFMA, no LDS) ----------------
// Q/K: packed [bh][n][64] rows = 32 hi | 32 lo. V: [bh][32][n] hi only.
__global__ __launch_bounds__(256) void qkv_proj(
    const float* __restrict__ W, const float* __restrict__ bias,
    const unsigned short* __restrict__ Xthi, const unsigned short* __restrict__ Xtlo,
    unsigned short* __restrict__ Qp, unsigned short* __restrict__ Kp,
    unsigned short* __restrict__ Vt) {
  const int t = threadIdx.x;
  const int w = t >> 6, lane = t & 63, m = lane & 15, hi4 = lane >> 4;
  const int o0 = blockIdx.x * 64, n0 = blockIdx.y * 64, b = blockIdx.z;

  const int orow = o0 + 16 * w + m;
  f32x4 zero = {0.f, 0.f, 0.f, 0.f};
  f32x4 acc[4] = {zero, zero, zero, zero};

  for (int cs = 0; cs < CIN; cs += 32) {
    const float* wp = &W[(size_t)orow * CIN + cs + 8 * hi4];
    float4 wa = *(const float4*)wp;
    float4 wb = *(const float4*)(wp + 4);
    float wf[8] = {wa.x, wa.y, wa.z, wa.w, wb.x, wb.y, wb.z, wb.w};
    bf16x8 awh, awl;
#pragma unroll
    for (int k = 0; k < 8; ++k) {
      unsigned short h = f2bf(wf[k]);
      awh[k] = (short)h;
      awl[k] = (short)f2bf(wf[k] - bf2f(h));
    }
#pragma unroll
    for (int jt = 0; jt < 4; ++jt) {
      size_t xi = ((size_t)b * NTOK + n0 + 16 * jt + m) * CIN + cs + 8 * hi4;
      bf16x8 bxh = *(const bf16x8*)&Xthi[xi];
      bf16x8 bxl = *(const bf16x8*)&Xtlo[xi];
      acc[jt] = __builtin_amdgcn_mfma_f32_16x16x32_bf16(awl, bxh, acc[jt], 0, 0, 0);
      acc[jt] = __builtin_amdgcn_mfma_f32_16x16x32_bf16(awh, bxl, acc[jt], 0, 0, 0);
      acc[jt] = __builtin_amdgcn_mfma_f32_16x16x32_bf16(awh, bxh, acc[jt], 0, 0, 0);
    }
  }

  const int qkv = o0 >> 8;
  const int ohd = (o0 & 255) + 16 * w;
  const int h = ohd >> 5;
  const int cb = (ohd & 31) + 4 * hi4;
  const int bh = b * NH + h;
  float bs[4];
#pragma unroll
  for (int r = 0; r < 4; ++r) bs[r] = bias[o0 + 16 * w + 4 * hi4 + r];

#pragma unroll
  for (int jt = 0; jt < 4; ++jt) {
    const int n = n0 + 16 * jt + m;
    unsigned short ph[4], pl[4];
#pragma unroll
    for (int r = 0; r < 4; ++r) {
      float y = acc[jt][r] + bs[r];
      if (qkv == 0) y *= QSCALE;  // fold softmax scale + log2e into Q
      ph[r] = f2bf(y);
      pl[r] = f2bf(y - bf2f(ph[r]));
    }
    if (qkv < 2) {  // Q/K packed: [bh][n][64] = 32 hi | 32 lo
      unsigned short* d = (qkv == 0 ? Qp : Kp);
      size_t idx = ((size_t)bh * NTOK + n) * 64 + cb;
      *(ushort4*)&d[idx]      = make_ushort4(ph[0], ph[1], ph[2], ph[3]);
      *(ushort4*)&d[idx + 32] = make_ushort4(pl[0], pl[1], pl[2], pl[3]);
    } else {  // V: [bh][32][n] hi only
#pragma unroll
      for (int r = 0; r < 4; ++r)
        Vt[((size_t)bh * HD + cb + r) * NTOK + n] = ph[r];
    }
  }
}

// ---------------- 3) Flash attention (shuffle-free PV, imm addressing) -----
// grid 1024 x 256 (4 independent waves). XCD swizzle: bh=(f&7)+8*((f>>3)&1),
// i0=(f>>4)*64. Lane 16g+m owns query i=16w+m; S^T rows j=16jt+4g+r.
// PV k-bijection: slot(g,s) <-> j = 32*k2 + 16*(s>>2) + 4g + (s&3)  =>
// B-frag = {pw[2k2][0], pw[2k2][1], pw[2k2+1][0], pw[2k2+1][1]} (lane-local),
// A-frag (V) loads the same permuted order: ushort4 at +0 and +16.
__global__ __launch_bounds__(256, 4) void attn_mfma(
    const unsigned short* __restrict__ Qp, const unsigned short* __restrict__ Kp,
    const unsigned short* __restrict__ Vt, float* __restrict__ out) {
  const int t = threadIdx.x;
  const int w = t >> 6, lane = t & 63, m = lane & 15, g = lane >> 4;
  const int f = blockIdx.x;
  const int i0 = (f >> 4) * 64;
  const int bh = (f & 7) + 8 * ((f >> 3) & 1);

  // Q fragments (once)
  const unsigned short* Qrow = Qp + ((size_t)bh * NTOK + i0 + 16 * w + m) * 64;
  const bf16x8 qh = *(const bf16x8*)&Qrow[8 * g];
  const bf16x8 ql = *(const bf16x8*)&Qrow[32 + 8 * g];

  // per-lane pointers (advanced by constant strides; loads use imm offsets)
  const unsigned short* pk  = Kp + (size_t)bh * NTOK * 64 + (size_t)m * 64 + 8 * g;
  const unsigned short* pk2 = pk + 32 * 64;                       // rows +32
  const unsigned short* pv0 = Vt + (size_t)bh * HD * NTOK + (size_t)m * NTOK + 4 * g;
  const unsigned short* pv1 = pv0 + 16 * NTOK;                    // ct=1

  f32x4 zero = {0.f, 0.f, 0.f, 0.f};
  f32x4 oacc[2] = {zero, zero};  // D[c=16ct+4g+r][i=m]
  float mrun = -1e30f;  // uniform across the 4 lanes of each query
  float lrun = 0.f;     // per-lane partial

  bf16x8 kf_h[4], kf_l[4];
  // preload tile 0 K
#pragma unroll
  for (int jt = 0; jt < 2; ++jt) {
    kf_h[jt] = *(const bf16x8*)(pk + jt * 1024);
    kf_l[jt] = *(const bf16x8*)(pk + jt * 1024 + 32);
    kf_h[jt + 2] = *(const bf16x8*)(pk2 + jt * 1024);
    kf_l[jt + 2] = *(const bf16x8*)(pk2 + jt * 1024 + 32);
  }
  pk += 4096; pk2 += 4096;

  for (int tile = 0; tile < NTOK / 64; ++tile) {
    // V loads for THIS tile (consumed after softmax, ~300cyc of cover)
    ushort4 v0a = *(const ushort4*)(pv0 + 0);
    ushort4 v0b = *(const ushort4*)(pv0 + 16);
    ushort4 v0c = *(const ushort4*)(pv0 + 32);
    ushort4 v0d = *(const ushort4*)(pv0 + 48);
    ushort4 v1a = *(const ushort4*)(pv1 + 0);
    ushort4 v1b = *(const ushort4*)(pv1 + 16);
    ushort4 v1c = *(const ushort4*)(pv1 + 32);
    ushort4 v1d = *(const ushort4*)(pv1 + 48);
    pv0 += 64; pv1 += 64;

    // ---- S^T tiles: rows j=16jt+4g+r, col i=m (3-pass split-bf16) ----
    f32x4 s[4];
#pragma unroll
    for (int jt = 0; jt < 4; ++jt) {
      f32x4 a = zero;
      a = __builtin_amdgcn_mfma_f32_16x16x32_bf16(kf_l[jt], qh, a, 0, 0, 0);
      a = __builtin_amdgcn_mfma_f32_16x16x32_bf16(kf_h[jt], ql, a, 0, 0, 0);
      a = __builtin_amdgcn_mfma_f32_16x16x32_bf16(kf_h[jt], qh, a, 0, 0, 0);
      s[jt] = a;
    }

    // prefetch NEXT tile's K (kf regs already consumed by the MFMAs above)
    if (tile + 1 < NTOK / 64) {
#pragma unroll
      for (int jt = 0; jt < 2; ++jt) {
        kf_h[jt] = *(const bf16x8*)(pk + jt * 1024);
        kf_l[jt] = *(const bf16x8*)(pk + jt * 1024 + 32);
        kf_h[jt + 2] = *(const bf16x8*)(pk2 + jt * 1024);
        kf_l[jt + 2] = *(const bf16x8*)(pk2 + jt * 1024 + 32);
      }
      pk += 4096; pk2 += 4096;
    }

    // ---- online softmax (defer-max; log2 domain) ----
    float mx = s[0][0];
#pragma unroll
    for (int jt = 0; jt < 4; ++jt)
#pragma unroll
      for (int r = 0; r < 4; ++r) mx = fmaxf(mx, s[jt][r]);
    if (!__all(mx <= mrun + DEFER_T)) {  // rare: real reduce + rescale
      float mr = mx;
      mr = fmaxf(mr, __shfl_xor(mr, 16, 64));
      mr = fmaxf(mr, __shfl_xor(mr, 32, 64));
      const float mnew = fmaxf(mrun, mr);
      const float sf = exp2f(mrun - mnew);
      lrun *= sf;
#pragma unroll
      for (int ct = 0; ct < 2; ++ct)
#pragma unroll
        for (int r = 0; r < 4; ++r) oacc[ct][r] *= sf;
      mrun = mnew;
    }

    float rsum = 0.f;
    unsigned pw[4][2];
#pragma unroll
    for (int jt = 0; jt < 4; ++jt) {
      float p0 = exp2f(s[jt][0] - mrun);
      float p1 = exp2f(s[jt][1] - mrun);
      float p2 = exp2f(s[jt][2] - mrun);
      float p3 = exp2f(s[jt][3] - mrun);
      rsum += (p0 + p1) + (p2 + p3);
      pw[jt][0] = packbf(p0, p1);
      pw[jt][1] = packbf(p2, p3);
    }
    lrun += rsum;

    // ---- PV: shuffle-free (custom j-bijection; A and B use the same) ----
#pragma unroll
    for (int k2 = 0; k2 < 2; ++k2) {
      union { unsigned u[4]; bf16x8 v; } pf;
      pf.u[0] = pw[2 * k2][0];
      pf.u[1] = pw[2 * k2][1];
      pf.u[2] = pw[2 * k2 + 1][0];
      pf.u[3] = pw[2 * k2 + 1][1];
      union { ushort4 h[2]; bf16x8 v; } va, vb;
      va.h[0] = (k2 == 0) ? v0a : v0c;
      va.h[1] = (k2 == 0) ? v0b : v0d;
      vb.h[0] = (k2 == 0) ? v1a : v1c;
      vb.h[1] = (k2 == 0) ? v1b : v1d;
      oacc[0] = __builtin_amdgcn_mfma_f32_16x16x32_bf16(va.v, pf.v, oacc[0], 0, 0, 0);
      oacc[1] = __builtin_amdgcn_mfma_f32_16x16x32_bf16(vb.v, pf.v, oacc[1], 0, 0, 0);
    }
  }

  // ---- epilogue: combine lane-partial l, divide, store ----
  lrun += __shfl_xor(lrun, 16, 64);
  lrun += __shfl_xor(lrun, 32, 64);
  const float inv = 1.0f / lrun;
  const int b = bh >> 3, h = bh & 7;
#pragma unroll
  for (int ct = 0; ct < 2; ++ct)
#pragma unroll
    for (int r = 0; r < 4; ++r) {
      const int c = h * HD + 16 * ct + 4 * g + r;
      out[((size_t)b * CIN + c) * NTOK + i0 + 16 * w + m] = oacc[ct][r] * inv;
    }
}

extern "C" void kernel_launch(void* const* d_in, const int* in_sizes, int n_in,
                              void* d_out, int out_size, void* d_ws, size_t ws_size,
                              hipStream_t stream) {
  const float* x    = (const float*)d_in[0];
  const float* w    = (const float*)d_in[1];
  const float* bias = (const float*)d_in[2];
  float* outp = (float*)d_out;

  // Xt (split bf16) in d_out scratch: 8,388,608 B = out bytes.
  unsigned short* Xthi = (unsigned short*)d_out;
  unsigned short* Xtlo = Xthi + (size_t)B_ * NTOK * CIN;

  // ws: Qp 8MB + Kp 8MB + Vt 4MB = 20.97MB (<= 25.17MB proven in r1-2)
  unsigned short* ws = (unsigned short*)d_ws;
  const size_t SZQK = (size_t)BH * NTOK * 64;
  unsigned short* Qp_ = ws;
  unsigned short* Kp_ = ws + SZQK;
  unsigned short* Vt_ = ws + 2 * SZQK;

  xt_split<<<dim3(NTOK / 64, CIN / 64, B_), 256, 0, stream>>>(x, Xthi, Xtlo);
  qkv_proj<<<dim3(COUT / 64, NTOK / 64, B_), 256, 0, stream>>>(
      w, bias, Xthi, Xtlo, Qp_, Kp_, Vt_);
  attn_mfma<<<dim3(1024), 256, 0, stream>>>(Qp_, Kp_, Vt_, outp);
}

// Round 8
// 305.946 us; speedup vs baseline: 1.6988x; 1.6988x over previous
//
#include <hip/hip_runtime.h>
#include <math.h>

// ClassicMHSA via split-bf16 MFMA, LDS-free flash attention (swapped QK^T).
// Round 8 = r5's PROVEN load structure + r7's shuffle-free PV + r6's cheap
// softmax. r7 post-mortem: removing the explicit double-buffer let the
// compiler sink the K prefetch to use (VGPR 64->40, all utils halved);
// packed K rows halved coalescing. So:
//   - K: separate Khi/Klo [bh][n][32] (16B loads, 1KB contiguous per wave),
//     explicit named double-buffer kf{0,1} (what kept r5's pipeline alive).
//   - V: TILE-PERMUTED layout so the shuffle-free PV A-fragment is 4 x 16B
//     contiguous loads: within each 64-token tile, token j = 32k2+16h2+4g+r
//     is stored at pos = 32k2+8g+4h2+r. PV B-frag = lane-local pw words
//     (r7 bijection, HW-verified by r7 passing). Zero cross-lane ops in PV.
//   - defer-max + per-lane-partial l + exp2 domain (r6, strictly less work).
//   - s_setprio(1) around MFMA clusters (T5, +4-7% on attn per guide m191).
//
//  1) xt_split : X[b][c][n] f32 -> Xthi/Xtlo [b][n][c] bf16
//  2) qkv_proj : MFMA GEMM -> Qhi/Qlo (Q pre-scaled), Khi/Klo [bh][n][32],
//                Vp [bh][32][n-permuted] (hi only)
//  3) attn_mfma: flash attention, QK^T 3-pass split-bf16, PV 1-pass bf16.

#define B_   2
#define CIN  256
#define COUT 768
#define NH   8
#define HD   32
#define NTOK 4096
#define BH   (B_*NH)

// log2(e)/sqrt(32): folds softmax scale + exp->exp2 conversion into Q.
#define QSCALE 0.2550565448497569f
// defer-max threshold in log2 units (P bounded by 2^12; lrun <= 2^22).
#define DEFER_T 12.0f

typedef __attribute__((ext_vector_type(8))) short bf16x8;
typedef __attribute__((ext_vector_type(4))) float f32x4;

static __device__ __forceinline__ unsigned short f2bf(float f) {  // RNE
  unsigned u = __float_as_uint(f);
  unsigned r = ((u >> 16) & 1u) + 0x7fffu;
  return (unsigned short)((u + r) >> 16);
}
static __device__ __forceinline__ float bf2f(unsigned short h) {
  return __uint_as_float(((unsigned)h) << 16);
}
// pack two POSITIVE floats to bf16 pair (round-half-up)
static __device__ __forceinline__ unsigned packbf(float lo, float hi) {
  unsigned a = (__float_as_uint(lo) + 0x8000u) >> 16;
  unsigned b = (__float_as_uint(hi) + 0x8000u) & 0xffff0000u;
  return a | b;
}

// ---------------- 1) X transpose + split (coalesced, LDS transpose) --------
__global__ __launch_bounds__(256) void xt_split(
    const float* __restrict__ X,
    unsigned short* __restrict__ Xthi, unsigned short* __restrict__ Xtlo) {
  __shared__ unsigned tile[64][72];  // hi | lo<<16
  const int t = threadIdx.x;
  const int n0 = blockIdx.x * 64, c0 = blockIdx.y * 64, b = blockIdx.z;
  {
    const int cl = t >> 2, nb = (t & 3) * 16;
    const float* src = &X[((size_t)(b * CIN + c0 + cl)) * NTOK + n0 + nb];
#pragma unroll
    for (int q = 0; q < 4; ++q) {
      float4 v = *(const float4*)&src[4 * q];
      float vv[4] = {v.x, v.y, v.z, v.w};
#pragma unroll
      for (int e = 0; e < 4; ++e) {
        unsigned short h = f2bf(vv[e]);
        unsigned short l = f2bf(vv[e] - bf2f(h));
        tile[cl][nb + 4 * q + e] = (unsigned)h | ((unsigned)l << 16);
      }
    }
  }
  __syncthreads();
  {
    const int nl = t >> 2, cb = (t & 3) * 16;
    unsigned wh[8], wl[8];
#pragma unroll
    for (int j = 0; j < 8; ++j) {
      unsigned a = tile[cb + 2 * j][nl];
      unsigned bb = tile[cb + 2 * j + 1][nl];
      wh[j] = (a & 0xffffu) | (bb << 16);
      wl[j] = (a >> 16) | (bb & 0xffff0000u);
    }
    size_t base = ((size_t)b * NTOK + n0 + nl) * CIN + c0 + cb;
    uint4 u0, u1;
    u0.x = wh[0]; u0.y = wh[1]; u0.z = wh[2]; u0.w = wh[3];
    u1.x = wh[4]; u1.y = wh[5]; u1.z = wh[6]; u1.w = wh[7];
    *(uint4*)&Xthi[base] = u0;
    *(uint4*)&Xthi[base + 8] = u1;
    u0.x = wl[0]; u0.y = wl[1]; u0.z = wl[2]; u0.w = wl[3];
    u1.x = wl[4]; u1.y = wl[5]; u1.z = wl[6]; u1.w = wl[7];
    *(uint4*)&Xtlo[base] = u0;
    *(uint4*)&Xtlo[base + 8] = u1;
  }
}

// ---------------- 2) QKV projection (MFMA, no LDS) ----------------
__global__ __launch_bounds__(256) void qkv_proj(
    const float* __restrict__ W, const float* __restrict__ bias,
    const unsigned short* __restrict__ Xthi, const unsigned short* __restrict__ Xtlo,
    unsigned short* __restrict__ Qhi, unsigned short* __restrict__ Qlo,
    unsigned short* __restrict__ Khi, unsigned short* __restrict__ Klo,
    unsigned short* __restrict__ Vp) {
  const int t = threadIdx.x;
  const int w = t >> 6, lane = t & 63, m = lane & 15, hi4 = lane >> 4;
  const int o0 = blockIdx.x * 64, n0 = blockIdx.y * 64, b = blockIdx.z;

  const int orow = o0 + 16 * w + m;
  f32x4 zero = {0.f, 0.f, 0.f, 0.f};
  f32x4 acc[4] = {zero, zero, zero, zero};

  for (int cs = 0; cs < CIN; cs += 32) {
    const float* wp = &W[(size_t)orow * CIN + cs + 8 * hi4];
    float4 wa = *(const float4*)wp;
    float4 wb = *(const float4*)(wp + 4);
    float wf[8] = {wa.x, wa.y, wa.z, wa.w, wb.x, wb.y, wb.z, wb.w};
    bf16x8 awh, awl;
#pragma unroll
    for (int k = 0; k < 8; ++k) {
      unsigned short h = f2bf(wf[k]);
      awh[k] = (short)h;
      awl[k] = (short)f2bf(wf[k] - bf2f(h));
    }
#pragma unroll
    for (int jt = 0; jt < 4; ++jt) {
      size_t xi = ((size_t)b * NTOK + n0 + 16 * jt + m) * CIN + cs + 8 * hi4;
      bf16x8 bxh = *(const bf16x8*)&Xthi[xi];
      bf16x8 bxl = *(const bf16x8*)&Xtlo[xi];
      acc[jt] = __builtin_amdgcn_mfma_f32_16x16x32_bf16(awl, bxh, acc[jt], 0, 0, 0);
      acc[jt] = __builtin_amdgcn_mfma_f32_16x16x32_bf16(awh, bxl, acc[jt], 0, 0, 0);
      acc[jt] = __builtin_amdgcn_mfma_f32_16x16x32_bf16(awh, bxh, acc[jt], 0, 0, 0);
    }
  }

  const int qkv = o0 >> 8;
  const int ohd = (o0 & 255) + 16 * w;
  const int h = ohd >> 5;
  const int cb = (ohd & 31) + 4 * hi4;
  const int bh = b * NH + h;
  float bs[4];
#pragma unroll
  for (int r = 0; r < 4; ++r) bs[r] = bias[o0 + 16 * w + 4 * hi4 + r];

#pragma unroll
  for (int jt = 0; jt < 4; ++jt) {
    const int n = n0 + 16 * jt + m;
    unsigned short ph[4], pl[4];
#pragma unroll
    for (int r = 0; r < 4; ++r) {
      float y = acc[jt][r] + bs[r];
      if (qkv == 0) y *= QSCALE;  // fold softmax scale + log2e into Q
      ph[r] = f2bf(y);
      pl[r] = f2bf(y - bf2f(ph[r]));
    }
    if (qkv < 2) {  // Q/K: [bh][n][32] hi+lo (separate, coalesced)
      unsigned short* dh = (qkv == 0 ? Qhi : Khi);
      unsigned short* dl = (qkv == 0 ? Qlo : Klo);
      size_t idx = ((size_t)bh * NTOK + n) * HD + cb;
      *(ushort4*)&dh[idx] = make_ushort4(ph[0], ph[1], ph[2], ph[3]);
      *(ushort4*)&dl[idx] = make_ushort4(pl[0], pl[1], pl[2], pl[3]);
    } else {  // V: tile-permuted [bh][32][n']: token 16jt+m -> pos below
      const int pos = ((jt >> 1) << 5) + ((m >> 2) << 3) + ((jt & 1) << 2) + (m & 3);
#pragma unroll
      for (int r = 0; r < 4; ++r)
        Vp[((size_t)bh * HD + cb + r) * NTOK + n0 + pos] = ph[r];
    }
  }
}

// ---------------- 3) Flash attention ----------------
// grid 1024 x 256 (4 independent waves). XCD swizzle: bh=(f&7)+8*((f>>3)&1),
// i0=(f>>4)*64. Lane 16g+m owns query i=16w+m; S^T rows j=16jt+4g+r.
// PV bijection: A/B slot (g,s=(h2,r)) <-> j = 32k2+16h2+4g+r. B-frag is the
// lane-local pw words; A-frag (V) is contiguous 16B in the permuted layout.
__global__ __launch_bounds__(256, 4) void attn_mfma(
    const unsigned short* __restrict__ Qhi, const unsigned short* __restrict__ Qlo,
    const unsigned short* __restrict__ Khi, const unsigned short* __restrict__ Klo,
    const unsigned short* __restrict__ Vp, float* __restrict__ out) {
  const int t = threadIdx.x;
  const int w = t >> 6, lane = t & 63, m = lane & 15, g = lane >> 4;
  const int f = blockIdx.x;
  const int i0 = (f >> 4) * 64;
  const int bh = (f & 7) + 8 * ((f >> 3) & 1);

  size_t qi = ((size_t)bh * NTOK + i0 + 16 * w + m) * HD + 8 * g;
  const bf16x8 qh = *(const bf16x8*)&Qhi[qi];
  const bf16x8 ql = *(const bf16x8*)&Qlo[qi];

  // per-lane pointers; all loads are base + imm (<= 3072B), ptrs advance by
  // constant strides per tile.
  const unsigned short* pkh = Khi + (size_t)bh * NTOK * HD + m * HD + 8 * g;
  const unsigned short* pkl = Klo + (size_t)bh * NTOK * HD + m * HD + 8 * g;
  const unsigned short* pv0 = Vp + (size_t)bh * HD * NTOK + m * NTOK + 8 * g;
  const unsigned short* pv1 = pv0 + 16 * NTOK;  // ct=1 rows

  f32x4 zero = {0.f, 0.f, 0.f, 0.f};
  f32x4 oacc[2] = {zero, zero};  // D[c=16ct+4g+r][i=m]
  float mrun = -1e30f;  // uniform across the 4 lanes of each query
  float lrun = 0.f;     // per-lane partial

  bf16x8 kh0[4], kl0[4], kh1[4], kl1[4];  // explicit K double-buffer

#define LOADK(KH, KL)                                        \
  do {                                                       \
    KH[0] = *(const bf16x8*)(pkh);                           \
    KH[1] = *(const bf16x8*)(pkh + 512);                     \
    KH[2] = *(const bf16x8*)(pkh + 1024);                    \
    KH[3] = *(const bf16x8*)(pkh + 1536);                    \
    KL[0] = *(const bf16x8*)(pkl);                           \
    KL[1] = *(const bf16x8*)(pkl + 512);                     \
    KL[2] = *(const bf16x8*)(pkl + 1024);                    \
    KL[3] = *(const bf16x8*)(pkl + 1536);                    \
    pkh += 2048; pkl += 2048;                                \
  } while (0)

#define COMPUTE_TILE(KH, KL)                                                   \
  do {                                                                         \
    /* V for THIS tile: 4 x 16B contiguous (permuted layout), consumed after   \
       softmax (~300cyc of cover) */                                           \
    bf16x8 v00 = *(const bf16x8*)(pv0);                                        \
    bf16x8 v01 = *(const bf16x8*)(pv0 + 32);                                   \
    bf16x8 v10 = *(const bf16x8*)(pv1);                                        \
    bf16x8 v11 = *(const bf16x8*)(pv1 + 32);                                   \
    pv0 += 64; pv1 += 64;                                                      \
    f32x4 s[4];                                                                \
    __builtin_amdgcn_s_setprio(1);                                             \
    _Pragma("unroll") for (int jt = 0; jt < 4; ++jt) {                         \
      f32x4 a = zero;                                                          \
      a = __builtin_amdgcn_mfma_f32_16x16x32_bf16(KL[jt], qh, a, 0, 0, 0);     \
      a = __builtin_amdgcn_mfma_f32_16x16x32_bf16(KH[jt], ql, a, 0, 0, 0);     \
      a = __builtin_amdgcn_mfma_f32_16x16x32_bf16(KH[jt], qh, a, 0, 0, 0);     \
      s[jt] = a;                                                               \
    }                                                                          \
    __builtin_amdgcn_s_setprio(0);                                             \
    float mx = s[0][0];                                                        \
    _Pragma("unroll") for (int jt = 0; jt < 4; ++jt)                           \
        _Pragma("unroll") for (int r = 0; r < 4; ++r) mx = fmaxf(mx, s[jt][r]);\
    if (!__all(mx <= mrun + DEFER_T)) { /* rare: real reduce + rescale */      \
      float mr = mx;                                                           \
      mr = fmaxf(mr, __shfl_xor(mr, 16, 64));                                  \
      mr = fmaxf(mr, __shfl_xor(mr, 32, 64));                                  \
      const float mnew = fmaxf(mrun, mr);                                      \
      const float sf = exp2f(mrun - mnew);                                     \
      lrun *= sf;                                                              \
      _Pragma("unroll") for (int ct = 0; ct < 2; ++ct)                         \
          _Pragma("unroll") for (int r = 0; r < 4; ++r) oacc[ct][r] *= sf;     \
      mrun = mnew;                                                             \
    }                                                                          \
    float rsum = 0.f;                                                          \
    unsigned pw[4][2];                                                         \
    _Pragma("unroll") for (int jt = 0; jt < 4; ++jt) {                         \
      float p0 = exp2f(s[jt][0] - mrun);                                       \
      float p1 = exp2f(s[jt][1] - mrun);                                       \
      float p2 = exp2f(s[jt][2] - mrun);                                       \
      float p3 = exp2f(s[jt][3] - mrun);                                       \
      rsum += (p0 + p1) + (p2 + p3);                                           \
      pw[jt][0] = packbf(p0, p1);                                              \
      pw[jt][1] = packbf(p2, p3);                                              \
    }                                                                          \
    lrun += rsum;                                                              \
    union { unsigned u[4]; bf16x8 v; } pf0, pf1;                               \
    pf0.u[0] = pw[0][0]; pf0.u[1] = pw[0][1];                                  \
    pf0.u[2] = pw[1][0]; pf0.u[3] = pw[1][1];                                  \
    pf1.u[0] = pw[2][0]; pf1.u[1] = pw[2][1];                                  \
    pf1.u[2] = pw[3][0]; pf1.u[3] = pw[3][1];                                  \
    __builtin_amdgcn_s_setprio(1);                                             \
    oacc[0] = __builtin_amdgcn_mfma_f32_16x16x32_bf16(v00, pf0.v, oacc[0], 0, 0, 0); \
    oacc[1] = __builtin_amdgcn_mfma_f32_16x16x32_bf16(v10, pf0.v, oacc[1], 0, 0, 0); \
    oacc[0] = __builtin_amdgcn_mfma_f32_16x16x32_bf16(v01, pf1.v, oacc[0], 0, 0, 0); \
    oacc[1] = __builtin_amdgcn_mfma_f32_16x16x32_bf16(v11, pf1.v, oacc[1], 0, 0, 0); \
    __builtin_amdgcn_s_setprio(0);                                             \
  } while (0)

  LOADK(kh0, kl0);  // tile 0
  for (int j0 = 0; j0 < NTOK; j0 += 128) {
    LOADK(kh1, kl1);      // prefetch tile +1 (in flight across COMPUTE 0)
    COMPUTE_TILE(kh0, kl0);
    LOADK(kh0, kl0);      // prefetch tile +2 (unconditional; last iter
                          // over-reads into the adjacent ws array - benign)
    COMPUTE_TILE(kh1, kl1);
  }
#undef LOADK
#undef COMPUTE_TILE

  // ---- epilogue: combine lane-partial l, divide, store ----
  lrun += __shfl_xor(lrun, 16, 64);
  lrun += __shfl_xor(lrun, 32, 64);
  const float inv = 1.0f / lrun;
  const int b = bh >> 3, h = bh & 7;
#pragma unroll
  for (int ct = 0; ct < 2; ++ct)
#pragma unroll
    for (int r = 0; r < 4; ++r) {
      const int c = h * HD + 16 * ct + 4 * g + r;
      out[((size_t)b * CIN + c) * NTOK + i0 + 16 * w + m] = oacc[ct][r] * inv;
    }
}

extern "C" void kernel_launch(void* const* d_in, const int* in_sizes, int n_in,
                              void* d_out, int out_size, void* d_ws, size_t ws_size,
                              hipStream_t stream) {
  const float* x    = (const float*)d_in[0];
  const float* w    = (const float*)d_in[1];
  const float* bias = (const float*)d_in[2];
  float* outp = (float*)d_out;

  // Xt (split bf16) in d_out scratch: 8,388,608 B = out bytes.
  unsigned short* Xthi = (unsigned short*)d_out;
  unsigned short* Xtlo = Xthi + (size_t)B_ * NTOK * CIN;

  // ws: Qhi,Qlo,Khi,Klo,Vp = 5 x 4MB = 20MB (<= 25.17MB proven in r1-2).
  // attn's last unconditional prefetch over-reads <=4KB past Khi/Klo/(never Vp)
  // slices - stays inside ws.
  unsigned short* ws = (unsigned short*)d_ws;
  const size_t SZ = (size_t)BH * NTOK * HD;
  unsigned short* Qhi_ = ws + 0 * SZ;
  unsigned short* Qlo_ = ws + 1 * SZ;
  unsigned short* Khi_ = ws + 2 * SZ;
  unsigned short* Klo_ = ws + 3 * SZ;
  unsigned short* Vp_  = ws + 4 * SZ;

  xt_split<<<dim3(NTOK / 64, CIN / 64, B_), 256, 0, stream>>>(x, Xthi, Xtlo);
  qkv_proj<<<dim3(COUT / 64, NTOK / 64, B_), 256, 0, stream>>>(
      w, bias, Xthi, Xtlo, Qhi_, Qlo_, Khi_, Klo_, Vp_);
  attn_mfma<<<dim3(1024), 256, 0, stream>>>(Qhi_, Qlo_, Khi_, Klo_, Vp_, outp);
}

// Round 9
// 183.692 us; speedup vs baseline: 2.8294x; 1.6655x over previous
//
#include <hip/hip_runtime.h>
#include <math.h>

// ClassicMHSA via split-bf16 MFMA, LDS-free flash attention (swapped QK^T).
// Round 9: r8 post-mortem found the real invariant — every r3..r8 variant
// moves 3.15GB through the per-CU L1/TA port (~12.3 TB/s aggregate, ~1
// transaction/cyc/CU), so per-tile ALU trims never mattered. This round
// halves traffic per unit work and kills the V scatter:
//   (a) 2 query-groups per wave (32 q/wave): K/V fragments loaded ONCE per
//       tile serve two QK/softmax/PV passes -> bytes per query-work halved.
//   (b) V stored in tile-fragment layout: per 64-token tile, 4 contiguous
//       1KB fragment blocks (elem ((ct*2+k2)<<9) + lane*8 + h2*4+r), so each
//       PV A-frag load is ONE coalesced 1KB transaction (was 16 segments).
// Keeps: XCD swizzle, explicit K double-buffer (r7 lesson), shuffle-free PV
// bijection (r7/r8-verified), defer-max + per-lane l + exp2 (r6), setprio.
//
//  1) xt_split : X[b][c][n] f32 -> Xthi/Xtlo [b][n][c] bf16
//  2) qkv_proj : MFMA GEMM -> Qhi/Qlo (Q pre-scaled), Khi/Klo [bh][n][32],
//                Vp [bh][tile][4x1KB frags] (hi only)
//  3) attn_mfma: flash attention, QK^T 3-pass split-bf16, PV 1-pass bf16.

#define B_   2
#define CIN  256
#define COUT 768
#define NH   8
#define HD   32
#define NTOK 4096
#define BH   (B_*NH)

// log2(e)/sqrt(32): folds softmax scale + exp->exp2 conversion into Q.
#define QSCALE 0.2550565448497569f
// defer-max threshold in log2 units (P bounded by 2^12; lrun <= 2^22).
#define DEFER_T 12.0f

typedef __attribute__((ext_vector_type(8))) short bf16x8;
typedef __attribute__((ext_vector_type(4))) float f32x4;

static __device__ __forceinline__ unsigned short f2bf(float f) {  // RNE
  unsigned u = __float_as_uint(f);
  unsigned r = ((u >> 16) & 1u) + 0x7fffu;
  return (unsigned short)((u + r) >> 16);
}
static __device__ __forceinline__ float bf2f(unsigned short h) {
  return __uint_as_float(((unsigned)h) << 16);
}
// pack two POSITIVE floats to bf16 pair (round-half-up)
static __device__ __forceinline__ unsigned packbf(float lo, float hi) {
  unsigned a = (__float_as_uint(lo) + 0x8000u) >> 16;
  unsigned b = (__float_as_uint(hi) + 0x8000u) & 0xffff0000u;
  return a | b;
}

// ---------------- 1) X transpose + split (coalesced, LDS transpose) --------
__global__ __launch_bounds__(256) void xt_split(
    const float* __restrict__ X,
    unsigned short* __restrict__ Xthi, unsigned short* __restrict__ Xtlo) {
  __shared__ unsigned tile[64][72];  // hi | lo<<16
  const int t = threadIdx.x;
  const int n0 = blockIdx.x * 64, c0 = blockIdx.y * 64, b = blockIdx.z;
  {
    const int cl = t >> 2, nb = (t & 3) * 16;
    const float* src = &X[((size_t)(b * CIN + c0 + cl)) * NTOK + n0 + nb];
#pragma unroll
    for (int q = 0; q < 4; ++q) {
      float4 v = *(const float4*)&src[4 * q];
      float vv[4] = {v.x, v.y, v.z, v.w};
#pragma unroll
      for (int e = 0; e < 4; ++e) {
        unsigned short h = f2bf(vv[e]);
        unsigned short l = f2bf(vv[e] - bf2f(h));
        tile[cl][nb + 4 * q + e] = (unsigned)h | ((unsigned)l << 16);
      }
    }
  }
  __syncthreads();
  {
    const int nl = t >> 2, cb = (t & 3) * 16;
    unsigned wh[8], wl[8];
#pragma unroll
    for (int j = 0; j < 8; ++j) {
      unsigned a = tile[cb + 2 * j][nl];
      unsigned bb = tile[cb + 2 * j + 1][nl];
      wh[j] = (a & 0xffffu) | (bb << 16);
      wl[j] = (a >> 16) | (bb & 0xffff0000u);
    }
    size_t base = ((size_t)b * NTOK + n0 + nl) * CIN + c0 + cb;
    uint4 u0, u1;
    u0.x = wh[0]; u0.y = wh[1]; u0.z = wh[2]; u0.w = wh[3];
    u1.x = wh[4]; u1.y = wh[5]; u1.z = wh[6]; u1.w = wh[7];
    *(uint4*)&Xthi[base] = u0;
    *(uint4*)&Xthi[base + 8] = u1;
    u0.x = wl[0]; u0.y = wl[1]; u0.z = wl[2]; u0.w = wl[3];
    u1.x = wl[4]; u1.y = wl[5]; u1.z = wl[6]; u1.w = wl[7];
    *(uint4*)&Xtlo[base] = u0;
    *(uint4*)&Xtlo[base + 8] = u1;
  }
}

// ---------------- 2) QKV projection (MFMA, no LDS) ----------------
__global__ __launch_bounds__(256) void qkv_proj(
    const float* __restrict__ W, const float* __restrict__ bias,
    const unsigned short* __restrict__ Xthi, const unsigned short* __restrict__ Xtlo,
    unsigned short* __restrict__ Qhi, unsigned short* __restrict__ Qlo,
    unsigned short* __restrict__ Khi, unsigned short* __restrict__ Klo,
    unsigned short* __restrict__ Vp) {
  const int t = threadIdx.x;
  const int w = t >> 6, lane = t & 63, m = lane & 15, hi4 = lane >> 4;
  const int o0 = blockIdx.x * 64, n0 = blockIdx.y * 64, b = blockIdx.z;

  const int orow = o0 + 16 * w + m;
  f32x4 zero = {0.f, 0.f, 0.f, 0.f};
  f32x4 acc[4] = {zero, zero, zero, zero};

  for (int cs = 0; cs < CIN; cs += 32) {
    const float* wp = &W[(size_t)orow * CIN + cs + 8 * hi4];
    float4 wa = *(const float4*)wp;
    float4 wb = *(const float4*)(wp + 4);
    float wf[8] = {wa.x, wa.y, wa.z, wa.w, wb.x, wb.y, wb.z, wb.w};
    bf16x8 awh, awl;
#pragma unroll
    for (int k = 0; k < 8; ++k) {
      unsigned short h = f2bf(wf[k]);
      awh[k] = (short)h;
      awl[k] = (short)f2bf(wf[k] - bf2f(h));
    }
#pragma unroll
    for (int jt = 0; jt < 4; ++jt) {
      size_t xi = ((size_t)b * NTOK + n0 + 16 * jt + m) * CIN + cs + 8 * hi4;
      bf16x8 bxh = *(const bf16x8*)&Xthi[xi];
      bf16x8 bxl = *(const bf16x8*)&Xtlo[xi];
      acc[jt] = __builtin_amdgcn_mfma_f32_16x16x32_bf16(awl, bxh, acc[jt], 0, 0, 0);
      acc[jt] = __builtin_amdgcn_mfma_f32_16x16x32_bf16(awh, bxl, acc[jt], 0, 0, 0);
      acc[jt] = __builtin_amdgcn_mfma_f32_16x16x32_bf16(awh, bxh, acc[jt], 0, 0, 0);
    }
  }

  const int qkv = o0 >> 8;
  const int ohd = (o0 & 255) + 16 * w;
  const int h = ohd >> 5;
  const int cb = (ohd & 31) + 4 * hi4;
  const int bh = b * NH + h;
  float bs[4];
#pragma unroll
  for (int r = 0; r < 4; ++r) bs[r] = bias[o0 + 16 * w + 4 * hi4 + r];

#pragma unroll
  for (int jt = 0; jt < 4; ++jt) {
    const int n = n0 + 16 * jt + m;
    unsigned short ph[4], pl[4];
#pragma unroll
    for (int r = 0; r < 4; ++r) {
      float y = acc[jt][r] + bs[r];
      if (qkv == 0) y *= QSCALE;  // fold softmax scale + log2e into Q
      ph[r] = f2bf(y);
      pl[r] = f2bf(y - bf2f(ph[r]));
    }
    if (qkv < 2) {  // Q/K: [bh][n][32] hi+lo (separate, coalesced)
      unsigned short* dh = (qkv == 0 ? Qhi : Khi);
      unsigned short* dl = (qkv == 0 ? Qlo : Klo);
      size_t idx = ((size_t)bh * NTOK + n) * HD + cb;
      *(ushort4*)&dh[idx] = make_ushort4(ph[0], ph[1], ph[2], ph[3]);
      *(ushort4*)&dl[idx] = make_ushort4(pl[0], pl[1], pl[2], pl[3]);
    } else {
      // V tile-fragment layout: per (bh, 64-tok tile) a 2048-elem block of
      // 4 x 512-elem frags (ct,k2); elem = frag<<9 | readerlane<<3 | h2*4+r.
      // reader lane (mm,gg) holds c=16ct+mm, tokens j=32k2+16h2+4gg+r.
      const int tau = 16 * jt + m;  // token within tile
      const int k2 = tau >> 5, h2 = (tau >> 4) & 1, gg = (tau >> 2) & 3, rm = tau & 3;
      const size_t vbase = (size_t)bh * (HD * NTOK) + (size_t)(n0 >> 6) * 2048;
#pragma unroll
      for (int r = 0; r < 4; ++r) {
        const int c = cb + r;
        const int ct = c >> 4, mm = c & 15;
        Vp[vbase + (size_t)(((ct * 2 + k2) << 9) + ((gg * 16 + mm) << 3) + h2 * 4 + rm)] = ph[r];
      }
    }
  }
}

// ---------------- 3) Flash attention (2 query-groups/wave) ----------------
// grid 512 x 256 (4 waves). XCD swizzle: bh=(f&7)+8*((f>>3)&1), i0=(f>>4)*128.
// Wave w: queries i0+32w+{0..15 (g0), 16..31 (g1)}; lane 16g+m owns query m of
// each group. K/V frags loaded once per tile, used by both groups.
__global__ __launch_bounds__(256, 2) void attn_mfma(
    const unsigned short* __restrict__ Qhi, const unsigned short* __restrict__ Qlo,
    const unsigned short* __restrict__ Khi, const unsigned short* __restrict__ Klo,
    const unsigned short* __restrict__ Vp, float* __restrict__ out) {
  const int t = threadIdx.x;
  const int w = t >> 6, lane = t & 63, m = lane & 15, g = lane >> 4;
  const int f = blockIdx.x;
  const int i0 = (f >> 4) * 128;
  const int bh = (f & 7) + 8 * ((f >> 3) & 1);

  size_t qi0 = ((size_t)bh * NTOK + i0 + 32 * w + m) * HD + 8 * g;
  const bf16x8 qh0 = *(const bf16x8*)&Qhi[qi0];
  const bf16x8 ql0 = *(const bf16x8*)&Qlo[qi0];
  const bf16x8 qh1 = *(const bf16x8*)&Qhi[qi0 + 16 * HD];
  const bf16x8 ql1 = *(const bf16x8*)&Qlo[qi0 + 16 * HD];

  const unsigned short* pkh = Khi + (size_t)bh * NTOK * HD + m * HD + 8 * g;
  const unsigned short* pkl = Klo + (size_t)bh * NTOK * HD + m * HD + 8 * g;
  const unsigned short* pv  = Vp + (size_t)bh * (HD * NTOK) + lane * 8;

  f32x4 zero = {0.f, 0.f, 0.f, 0.f};
  f32x4 oa00 = zero, oa01 = zero;  // group0: ct=0,1   D[c=16ct+4g+r][i=m]
  f32x4 oa10 = zero, oa11 = zero;  // group1
  float mrun0 = -1e30f, lrun0 = 0.f;
  float mrun1 = -1e30f, lrun1 = 0.f;

  bf16x8 kh0[4], kl0[4], kh1[4], kl1[4];  // explicit K double-buffer

#define LOADK(KH, KL)                                        \
  do {                                                       \
    KH[0] = *(const bf16x8*)(pkh);                           \
    KH[1] = *(const bf16x8*)(pkh + 512);                     \
    KH[2] = *(const bf16x8*)(pkh + 1024);                    \
    KH[3] = *(const bf16x8*)(pkh + 1536);                    \
    KL[0] = *(const bf16x8*)(pkl);                           \
    KL[1] = *(const bf16x8*)(pkl + 512);                     \
    KL[2] = *(const bf16x8*)(pkl + 1024);                    \
    KL[3] = *(const bf16x8*)(pkl + 1536);                    \
    pkh += 2048; pkl += 2048;                                \
  } while (0)

#define QK_GRP(KH, KL, QH, QL, S)                                              \
  do {                                                                         \
    __builtin_amdgcn_s_setprio(1);                                             \
    _Pragma("unroll") for (int jt = 0; jt < 4; ++jt) {                         \
      f32x4 a = zero;                                                          \
      a = __builtin_amdgcn_mfma_f32_16x16x32_bf16(KL[jt], QH, a, 0, 0, 0);     \
      a = __builtin_amdgcn_mfma_f32_16x16x32_bf16(KH[jt], QL, a, 0, 0, 0);     \
      a = __builtin_amdgcn_mfma_f32_16x16x32_bf16(KH[jt], QH, a, 0, 0, 0);     \
      S[jt] = a;                                                               \
    }                                                                          \
    __builtin_amdgcn_s_setprio(0);                                             \
  } while (0)

#define SM_PV(S, MRUN, LRUN, OC0, OC1, V00, V01, V10, V11)                     \
  do {                                                                         \
    float mx = fmaxf(fmaxf(S[0][0], S[0][1]), fmaxf(S[0][2], S[0][3]));        \
    _Pragma("unroll") for (int jt = 1; jt < 4; ++jt)                           \
      mx = fmaxf(mx, fmaxf(fmaxf(S[jt][0], S[jt][1]),                          \
                           fmaxf(S[jt][2], S[jt][3])));                        \
    if (!__all(mx <= MRUN + DEFER_T)) { /* rare: real reduce + rescale */      \
      float mr = mx;                                                           \
      mr = fmaxf(mr, __shfl_xor(mr, 16, 64));                                  \
      mr = fmaxf(mr, __shfl_xor(mr, 32, 64));                                  \
      const float mnew = fmaxf(MRUN, mr);                                      \
      const float sf = exp2f(MRUN - mnew);                                     \
      LRUN *= sf;                                                              \
      OC0 = OC0 * sf; OC1 = OC1 * sf;                                          \
      MRUN = mnew;                                                             \
    }                                                                          \
    float rsum = 0.f;                                                          \
    unsigned pw[4][2];                                                         \
    _Pragma("unroll") for (int jt = 0; jt < 4; ++jt) {                         \
      float p0 = exp2f(S[jt][0] - MRUN);                                       \
      float p1 = exp2f(S[jt][1] - MRUN);                                       \
      float p2 = exp2f(S[jt][2] - MRUN);                                       \
      float p3 = exp2f(S[jt][3] - MRUN);                                       \
      rsum += (p0 + p1) + (p2 + p3);                                           \
      pw[jt][0] = packbf(p0, p1);                                              \
      pw[jt][1] = packbf(p2, p3);                                              \
    }                                                                          \
    LRUN += rsum;                                                              \
    union { unsigned u[4]; bf16x8 v; } pf0, pf1;                               \
    pf0.u[0] = pw[0][0]; pf0.u[1] = pw[0][1];                                  \
    pf0.u[2] = pw[1][0]; pf0.u[3] = pw[1][1];                                  \
    pf1.u[0] = pw[2][0]; pf1.u[1] = pw[2][1];                                  \
    pf1.u[2] = pw[3][0]; pf1.u[3] = pw[3][1];                                  \
    __builtin_amdgcn_s_setprio(1);                                             \
    OC0 = __builtin_amdgcn_mfma_f32_16x16x32_bf16(V00, pf0.v, OC0, 0, 0, 0);   \
    OC1 = __builtin_amdgcn_mfma_f32_16x16x32_bf16(V10, pf0.v, OC1, 0, 0, 0);   \
    OC0 = __builtin_amdgcn_mfma_f32_16x16x32_bf16(V01, pf1.v, OC0, 0, 0, 0);   \
    OC1 = __builtin_amdgcn_mfma_f32_16x16x32_bf16(V11, pf1.v, OC1, 0, 0, 0);   \
    __builtin_amdgcn_s_setprio(0);                                             \
  } while (0)

#define COMPUTE_TILE(KH, KL)                                                   \
  do {                                                                         \
    bf16x8 v00 = *(const bf16x8*)(pv);         /* (ct0,k2=0) */                \
    bf16x8 v01 = *(const bf16x8*)(pv + 512);   /* (ct0,k2=1) */                \
    bf16x8 v10 = *(const bf16x8*)(pv + 1024);  /* (ct1,k2=0) */                \
    bf16x8 v11 = *(const bf16x8*)(pv + 1536);  /* (ct1,k2=1) */                \
    pv += 2048;                                                                \
    {                                                                          \
      f32x4 s[4];                                                              \
      QK_GRP(KH, KL, qh0, ql0, s);                                             \
      SM_PV(s, mrun0, lrun0, oa00, oa01, v00, v01, v10, v11);                  \
    }                                                                          \
    {                                                                          \
      f32x4 s[4];                                                              \
      QK_GRP(KH, KL, qh1, ql1, s);                                             \
      SM_PV(s, mrun1, lrun1, oa10, oa11, v00, v01, v10, v11);                  \
    }                                                                          \
  } while (0)

  LOADK(kh0, kl0);  // tile 0
  for (int j0 = 0; j0 < NTOK; j0 += 128) {
    LOADK(kh1, kl1);      // prefetch tile +1 (in flight across COMPUTE 0)
    COMPUTE_TILE(kh0, kl0);
    LOADK(kh0, kl0);      // prefetch tile +2 (last iter over-reads into the
                          // adjacent ws array - benign)
    COMPUTE_TILE(kh1, kl1);
  }
#undef LOADK
#undef QK_GRP
#undef SM_PV
#undef COMPUTE_TILE

  // ---- epilogue: combine lane-partial l, divide, store ----
  lrun0 += __shfl_xor(lrun0, 16, 64);
  lrun0 += __shfl_xor(lrun0, 32, 64);
  lrun1 += __shfl_xor(lrun1, 16, 64);
  lrun1 += __shfl_xor(lrun1, 32, 64);
  const float inv0 = 1.0f / lrun0;
  const float inv1 = 1.0f / lrun1;
  const int b = bh >> 3, h = bh & 7;
  float* og = out + (size_t)b * CIN * NTOK + i0 + 32 * w + m;
#pragma unroll
  for (int r = 0; r < 4; ++r) {
    const int c0 = h * HD + 4 * g + r;        // ct=0
    const int c1 = h * HD + 16 + 4 * g + r;   // ct=1
    og[(size_t)c0 * NTOK]      = oa00[r] * inv0;
    og[(size_t)c1 * NTOK]      = oa01[r] * inv0;
    og[(size_t)c0 * NTOK + 16] = oa10[r] * inv1;
    og[(size_t)c1 * NTOK + 16] = oa11[r] * inv1;
  }
}

extern "C" void kernel_launch(void* const* d_in, const int* in_sizes, int n_in,
                              void* d_out, int out_size, void* d_ws, size_t ws_size,
                              hipStream_t stream) {
  const float* x    = (const float*)d_in[0];
  const float* w    = (const float*)d_in[1];
  const float* bias = (const float*)d_in[2];
  float* outp = (float*)d_out;

  // Xt (split bf16) in d_out scratch: 8,388,608 B = out bytes.
  unsigned short* Xthi = (unsigned short*)d_out;
  unsigned short* Xtlo = Xthi + (size_t)B_ * NTOK * CIN;

  // ws: Qhi,Qlo,Khi,Klo,Vp = 5 x 4MB = 20MB (<= 25.17MB proven in r1-2).
  // attn's last unconditional K prefetch over-reads <=4KB past the Khi/Klo
  // slice ends - stays inside ws.
  unsigned short* ws = (unsigned short*)d_ws;
  const size_t SZ = (size_t)BH * NTOK * HD;
  unsigned short* Qhi_ = ws + 0 * SZ;
  unsigned short* Qlo_ = ws + 1 * SZ;
  unsigned short* Khi_ = ws + 2 * SZ;
  unsigned short* Klo_ = ws + 3 * SZ;
  unsigned short* Vp_  = ws + 4 * SZ;

  xt_split<<<dim3(NTOK / 64, CIN / 64, B_), 256, 0, stream>>>(x, Xthi, Xtlo);
  qkv_proj<<<dim3(COUT / 64, NTOK / 64, B_), 256, 0, stream>>>(
      w, bias, Xthi, Xtlo, Qhi_, Qlo_, Khi_, Klo_, Vp_);
  attn_mfma<<<dim3(512), 256, 0, stream>>>(Qhi_, Qlo_, Khi_, Klo_, Vp_, outp);
}